// Round 7
// baseline (30.492 us; speedup 1.0000x reference)
//
#include <hip/hip_runtime.h>

// GAE backward recurrence, v6 (2 envs/block, cross-env prefetch, raw barriers).
//   adv[t] = delta[t] + c[t] * adv[t+1],  c[t] = (1-first[t+1])*gamma*lambda
//   delta[t] = r[t] + (1-first[t+1])*gamma*V[t+1] - V[t]
// Diagnosis (R2-R5 all ~30us): not BW-bound (3.8 of 6.3 TB/s), not VALU-bound
// (8%), not conflict-bound. Hypothesis: __syncthreads' full vmcnt(0) drain +
// short-lived blocks serialize load-latency with compute phases.
// Fix: 2048 blocks x 2 envs. Env-1 inputs are prefetched into registers while
// env-0 runs its scan/store phases. Barriers are raw s_barrier with manual
// lgkmcnt(0)-only drain, so prefetch loads (and output stores) stay in flight
// across barriers. All 8 blocks/CU co-resident (LDS 16.4KB).

constexpr int NE   = 4096;
constexpr int NT   = 2048;
constexpr int NT1  = 2049;
constexpr float GAMMA  = 0.99f;
constexpr float LAMBDA = 0.95f;
constexpr int TPB = 256;
constexpr int PER = NT / TPB;    // 8 timesteps per thread (phase 2 segment)
constexpr int NQ  = NT / 4;      // 512 float4 granules per env
constexpr int QPT = NQ / TPB;    // 2 granules per thread (phases 1 & 3)
constexpr int EPB = 2;           // envs per block
constexpr int NB  = NE / EPB;    // 2048 blocks

typedef float f32x4 __attribute__((ext_vector_type(4)));
typedef float f32x4u __attribute__((ext_vector_type(4), aligned(4)));

__device__ __forceinline__ f32x4 ld4u(const float* p) {
    return (f32x4)*reinterpret_cast<const f32x4u*>(p);
}

// 16B-granule XOR swizzle: <=2-way (free) for lane-consecutive (ph 1/3) and
// lane-stride-2 (ph 2) granule access.
__device__ __forceinline__ int swz(int g) { return g ^ ((g >> 3) & 7); }

// Barrier that drains ONLY LDS ops (lgkmcnt); global loads/stores stay in
// flight. sched_barrier(0) on both sides pins ordering (rule #18).
__device__ __forceinline__ void bar_lds() {
    asm volatile("s_waitcnt lgkmcnt(0)" ::: "memory");
    __builtin_amdgcn_sched_barrier(0);
    __builtin_amdgcn_s_barrier();
    __builtin_amdgcn_sched_barrier(0);
}

struct Env { f32x4 r[QPT], v[QPT], f[QPT]; float vn[QPT]; };

__device__ __forceinline__ void load_env(int e, int tid, int lane,
    const float* __restrict__ rewards, const float* __restrict__ values,
    const float* __restrict__ first, Env& E)
{
    const float* r_row = rewards + (size_t)e * NT;
    const float* v_row = values  + (size_t)e * NT1;
    const float* f_row = first   + (size_t)e * NT1;
#pragma unroll
    for (int j = 0; j < QPT; ++j) {
        const int t = 4 * (j * TPB + tid);
        E.r[j] = *reinterpret_cast<const f32x4*>(r_row + t);  // 16B aligned
        E.v[j] = ld4u(v_row + t);        // v[t..t+3]
        E.f[j] = ld4u(f_row + t + 1);    // f[t+1..t+4]
        E.vn[j] = (lane == 63) ? v_row[t + 4] : 0.0f;  // cross-wave patch
    }
}

__device__ __forceinline__ void phase1(const Env& E, int tid, int lane,
    f32x4* d_lds, f32x4* c_lds, f32x4 vreg[QPT])
{
#pragma unroll
    for (int j = 0; j < QPT; ++j) {
        const int q = j * TPB + tid;
        float vnext = __shfl_down(E.v[j].x, 1);
        if (lane == 63) vnext = E.vn[j];
        f32x4 v4b; v4b.x = E.v[j].y; v4b.y = E.v[j].z; v4b.z = E.v[j].w; v4b.w = vnext;
        const f32x4 nl = 1.0f - E.f[j];
        d_lds[swz(q)] = E.r[j] + nl * GAMMA * v4b - E.v[j];
        c_lds[swz(q)] = nl * (GAMMA * LAMBDA);
        vreg[j] = E.v[j];
    }
}

__device__ __forceinline__ void phase23(int e, int tid, int lane, int w,
    f32x4* d_lds, f32x4* c_lds, float* sWA, float* sWB,
    const f32x4 vreg[QPT], float* __restrict__ out)
{
    // ---- Phase 2: per-thread contiguous 8-step segment ----
    float d[PER], c[PER];
    {
        const f32x4 da = d_lds[swz(2 * tid)];
        const f32x4 db = d_lds[swz(2 * tid + 1)];
        const f32x4 ca = c_lds[swz(2 * tid)];
        const f32x4 cb = c_lds[swz(2 * tid + 1)];
        d[0]=da.x; d[1]=da.y; d[2]=da.z; d[3]=da.w;
        d[4]=db.x; d[5]=db.y; d[6]=db.z; d[7]=db.w;
        c[0]=ca.x; c[1]=ca.y; c[2]=ca.z; c[3]=ca.w;
        c[4]=cb.x; c[5]=cb.y; c[6]=cb.z; c[7]=cb.w;
    }

    // Local linear function: x -> A*x + B
    float A = 1.0f, B = 0.0f;
#pragma unroll
    for (int k = PER - 1; k >= 0; --k) {
        B = fmaf(c[k], B, d[k]);
        A *= c[k];
    }

    // Wave-level inclusive suffix scan via shuffles.
    float cA = A, cB = B;
#pragma unroll
    for (int off = 1; off < 64; off <<= 1) {
        const float a2 = __shfl_down(cA, off);
        const float b2 = __shfl_down(cB, off);
        if (lane + off < 64) {
            cB = fmaf(cA, b2, cB);
            cA = cA * a2;
        }
    }

    if (lane == 0) { sWA[w] = cA; sWB[w] = cB; }

    // Exclusive-within-wave (suffix from lane+1).
    float EA = __shfl_down(cA, 1);
    float EB = __shfl_down(cB, 1);
    if (lane == 63) { EA = 1.0f; EB = 0.0f; }

    bar_lds();

    // Tail composition of later waves.
    float TB = 0.0f;
    for (int u = 3; u > w; --u) TB = fmaf(sWA[u], TB, sWB[u]);
    float x = fmaf(EA, TB, EB);

    // Replay local recurrence; stash adv back into d_lds.
    float adv[PER];
#pragma unroll
    for (int k = PER - 1; k >= 0; --k) {
        x = fmaf(c[k], x, d[k]);
        adv[k] = x;
    }
    {
        f32x4 a0; a0.x=adv[0]; a0.y=adv[1]; a0.z=adv[2]; a0.w=adv[3];
        f32x4 a1; a1.x=adv[4]; a1.y=adv[5]; a1.z=adv[6]; a1.w=adv[7];
        d_lds[swz(2 * tid)]     = a0;
        d_lds[swz(2 * tid + 1)] = a1;
    }
    bar_lds();

    // ---- Phase 3: nontemporal coalesced float4 stores ----
    float* __restrict__ adv_out = out + (size_t)e * NT;
    float* __restrict__ vt_out  = out + (size_t)NE * NT + (size_t)e * NT;
#pragma unroll
    for (int j = 0; j < QPT; ++j) {
        const int q = j * TPB + tid;
        const int t = 4 * q;
        const f32x4 a4 = d_lds[swz(q)];
        const f32x4 vt = vreg[j] + a4;
        __builtin_nontemporal_store(a4, reinterpret_cast<f32x4*>(adv_out + t));
        __builtin_nontemporal_store(vt, reinterpret_cast<f32x4*>(vt_out + t));
    }
}

__global__ __launch_bounds__(TPB) void gae_kernel(
    const float* __restrict__ rewards,   // [NE, NT]
    const float* __restrict__ values,    // [NE, NT+1]
    const float* __restrict__ first,     // [NE, NT+1]
    float* __restrict__ out)             // [adv(NE*NT), vtarg(NE*NT)]
{
    __shared__ f32x4 d_lds[NQ];
    __shared__ f32x4 c_lds[NQ];
    __shared__ float sWA[4];
    __shared__ float sWB[4];

    const int b    = blockIdx.x;
    const int tid  = threadIdx.x;
    const int lane = tid & 63;
    const int w    = tid >> 6;

    f32x4 vreg0[QPT], vreg1[QPT];

    // ---- env 0 ----
    Env P;
    load_env(b, tid, lane, rewards, values, first, P);
    phase1(P, tid, lane, d_lds, c_lds, vreg0);

    // Prefetch env 1 NOW; loads stay in flight across all env-0 barriers
    // (bar_lds drains lgkmcnt only, never vmcnt).
    Env Q;
    load_env(b + NB, tid, lane, rewards, values, first, Q);

    bar_lds();
    phase23(b, tid, lane, w, d_lds, c_lds, sWA, sWB, vreg0, out);
    bar_lds();   // WAR: env-0 phase-3 LDS reads done before env-1 writes

    // ---- env 1 ----
    phase1(Q, tid, lane, d_lds, c_lds, vreg1);
    bar_lds();
    phase23(b + NB, tid, lane, w, d_lds, c_lds, sWA, sWB, vreg1, out);
}

extern "C" void kernel_launch(void* const* d_in, const int* in_sizes, int n_in,
                              void* d_out, int out_size, void* d_ws, size_t ws_size,
                              hipStream_t stream) {
    const float* rewards = (const float*)d_in[0];
    const float* values  = (const float*)d_in[1];
    const float* first   = (const float*)d_in[2];
    float* out = (float*)d_out;
    gae_kernel<<<NB, TPB, 0, stream>>>(rewards, values, first, out);
}

// Round 8
// 30.071 us; speedup vs baseline: 1.0140x; 1.0140x over previous
//
#include <hip/hip_runtime.h>

// GAE backward recurrence, v7: wave-autonomous, zero LDS, zero barriers.
//   adv[t] = delta[t] + c[t] * adv[t+1],  c[t] = (1-first[t+1])*gamma*lambda
//   delta[t] = r[t] + (1-first[t+1])*gamma*V[t+1] - V[t]
// One WAVE per env (4096 waves, 1024 blocks x 256 threads). Each wave walks
// its env backward in 8 granules of 256 timesteps (lane l owns 4 consecutive
// t's). Per granule: local 4-step compose -> 6-round shuffle suffix scan ->
// carry chain via lane-0 broadcast. Loads are a depth-3 register pipeline;
// no __syncthreads / LDS anywhere, so no vmcnt(0) drain points: the memory
// pipe streams continuously. Decisive test of the generation-serialization
// theory (R2-R6 all ~30us regardless of structure).

constexpr int NE   = 4096;
constexpr int NT   = 2048;
constexpr int NT1  = 2049;
constexpr float GAMMA  = 0.99f;
constexpr float LAMBDA = 0.95f;
constexpr int TPB = 256;
constexpr int NG  = NT / 256;   // 8 granules (256 timesteps each) per env

typedef float f32x4 __attribute__((ext_vector_type(4)));
typedef float f32x4u __attribute__((ext_vector_type(4), aligned(4)));

__device__ __forceinline__ f32x4 ld4u(const float* p) {
    return (f32x4)*reinterpret_cast<const f32x4u*>(p);
}

__global__ __launch_bounds__(TPB) void gae_kernel(
    const float* __restrict__ rewards,   // [NE, NT]
    const float* __restrict__ values,    // [NE, NT+1]
    const float* __restrict__ first,     // [NE, NT+1]
    float* __restrict__ out)             // [adv(NE*NT), vtarg(NE*NT)]
{
    const int tid  = threadIdx.x;
    const int lane = tid & 63;
    const int w    = tid >> 6;
    const int e    = blockIdx.x * 4 + w;      // one env per wave

    const float* r_row = rewards + (size_t)e * NT;
    const float* v_row = values  + (size_t)e * NT1;
    const float* f_row = first   + (size_t)e * NT1;
    float* adv_out = out + (size_t)e * NT;
    float* vt_out  = out + (size_t)NE * NT + (size_t)e * NT;

    const int l4 = lane * 4;

    // Depth-3 register pipeline over granules (processed g = 7 .. 0).
    f32x4 rb[3], vb[3], fb[3];
#define LOADG(s, g)                                                     \
    do {                                                                \
        const int _t = (g) * 256 + l4;                                  \
        rb[s] = *reinterpret_cast<const f32x4*>(r_row + _t);            \
        vb[s] = ld4u(v_row + _t);                                       \
        fb[s] = ld4u(f_row + _t + 1);                                   \
    } while (0)

    LOADG(0, 7); LOADG(1, 6); LOADG(2, 5);

    float carry   = 0.0f;         // adv[(g+1)*256] flowing down the granules
    float prevTop = v_row[NT];    // v[(g+1)*256] for lane 63's v[t+4]

#pragma unroll
    for (int g = NG - 1; g >= 0; --g) {
        const int s = (NG - 1 - g) % 3;           // constant after unroll
        const f32x4 r4 = rb[s];
        const f32x4 v4 = vb[s];
        const f32x4 f4 = fb[s];
        if (g >= 3) LOADG(s, g - 3);              // prefetch 3 granules ahead

        // v[t+4]: next lane's v4.x; lane 63 takes granule g+1's lane-0 v4.x.
        float vnext = __shfl_down(v4.x, 1);
        const float top = __shfl(v4.x, 0);        // v[g*256], for next iter
        if (lane == 63) vnext = prevTop;
        prevTop = top;

        const f32x4 nl = 1.0f - f4;
        f32x4 v4b; v4b.x = v4.y; v4b.y = v4.z; v4b.z = v4.w; v4b.w = vnext;
        const f32x4 d4 = r4 + nl * GAMMA * v4b - v4;
        const f32x4 c4 = nl * (GAMMA * LAMBDA);

        // Local linear function over lane's 4 steps: x_in -> A*x_in + B
        const float B = d4.x + c4.x * (d4.y + c4.y * (d4.z + c4.z * d4.w));
        const float A = c4.x * c4.y * c4.z * c4.w;

        // Wave inclusive suffix scan (lane l composes lanes l..63).
        float cA = A, cB = B;
#pragma unroll
        for (int off = 1; off < 64; off <<= 1) {
            const float a2 = __shfl_down(cA, off);
            const float b2 = __shfl_down(cB, off);
            if (lane + off < 64) {
                cB = fmaf(cA, b2, cB);
                cA = cA * a2;
            }
        }
        // Exclusive (suffix from lane+1) and whole-granule carry update.
        float EA = __shfl_down(cA, 1);
        float EB = __shfl_down(cB, 1);
        if (lane == 63) { EA = 1.0f; EB = 0.0f; }
        const float newcarry = fmaf(__shfl(cA, 0), carry, __shfl(cB, 0));
        float x = fmaf(EA, carry, EB);            // adv at lane's t0+4
        carry = newcarry;

        // Replay the 4 local steps; a4 = adv[t0..t0+3].
        f32x4 a4;
        x = fmaf(c4.w, x, d4.w); a4.w = x;
        x = fmaf(c4.z, x, d4.z); a4.z = x;
        x = fmaf(c4.y, x, d4.y); a4.y = x;
        x = fmaf(c4.x, x, d4.x); a4.x = x;
        const f32x4 vt = v4 + a4;

        const int t = g * 256 + l4;
        __builtin_nontemporal_store(a4, reinterpret_cast<f32x4*>(adv_out + t));
        __builtin_nontemporal_store(vt, reinterpret_cast<f32x4*>(vt_out + t));
    }
#undef LOADG
}

extern "C" void kernel_launch(void* const* d_in, const int* in_sizes, int n_in,
                              void* d_out, int out_size, void* d_ws, size_t ws_size,
                              hipStream_t stream) {
    const float* rewards = (const float*)d_in[0];
    const float* values  = (const float*)d_in[1];
    const float* first   = (const float*)d_in[2];
    float* out = (float*)d_out;
    gae_kernel<<<NE / 4, TPB, 0, stream>>>(rewards, values, first, out);
}